// Round 1
// baseline (159.752 us; speedup 1.0000x reference)
//
#include <hip/hip_runtime.h>

// Problem constants (from reference setup_inputs): B=32, T=1024, D=768.
// D and T are re-derived from in_sizes for safety; B is fixed by the problem.
#define BATCH 32

// ---------------------------------------------------------------------------
// Kernel 1: per-row inclusive cumsum of dur [B, T] -> cs [B, T] in workspace.
// One block of T threads per batch row, Hillis-Steele scan in LDS.
// ---------------------------------------------------------------------------
__global__ void cumsum_kernel(const int* __restrict__ dur, int* __restrict__ cs, int T) {
    extern __shared__ int s[];
    const int b = blockIdx.x;
    const int tid = threadIdx.x;
    s[tid] = dur[b * T + tid];
    __syncthreads();
    for (int off = 1; off < T; off <<= 1) {
        int v = 0;
        if (tid >= off) v = s[tid - off];
        __syncthreads();
        s[tid] += v;
        __syncthreads();
    }
    cs[b * T + tid] = s[tid];
}

// ---------------------------------------------------------------------------
// Kernel 2: expand. One 64-lane wave per output frame.
// blockDim = (64, 4): threadIdx.y selects the wave's frame.
// grid = (ceil(max_len/4), B).
// Each wave: binary-search cumsum row for the source frame, then float4-copy
// 768 floats (192 float4, 3 per lane). Rows past total[b] get zeros.
// ---------------------------------------------------------------------------
__global__ void expand_kernel(const float* __restrict__ x,
                              const int* __restrict__ cs,
                              float* __restrict__ out,
                              int T, int D, int max_len) {
    const int b = blockIdx.y;
    const int t = blockIdx.x * blockDim.y + threadIdx.y;  // output frame index
    if (t >= max_len) return;

    const int lane = threadIdx.x;  // 0..63
    const int* __restrict__ csrow = cs + b * T;
    const int total = csrow[T - 1];

    const int d4 = D >> 2;  // float4 count per frame (192)
    float4* __restrict__ dst = reinterpret_cast<float4*>(out + ((size_t)b * max_len + t) * D);

    if (t >= total) {
        const float4 z = make_float4(0.f, 0.f, 0.f, 0.f);
        for (int k = lane; k < d4; k += 64) dst[k] = z;
        return;
    }

    // searchsorted(cs, t, side='right'): smallest i with cs[i] > t
    int lo = 0, hi = T;
    while (lo < hi) {
        int mid = (lo + hi) >> 1;
        if (csrow[mid] <= t) lo = mid + 1; else hi = mid;
    }
    const int src = lo;  // < T guaranteed since t < total == cs[T-1]

    const float4* __restrict__ sp =
        reinterpret_cast<const float4*>(x + ((size_t)b * T + src) * D);
    for (int k = lane; k < d4; k += 64) dst[k] = sp[k];
}

extern "C" void kernel_launch(void* const* d_in, const int* in_sizes, int n_in,
                              void* d_out, int out_size, void* d_ws, size_t ws_size,
                              hipStream_t stream) {
    const float* x = (const float*)d_in[0];
    const int* dur = (const int*)d_in[1];
    float* out = (float*)d_out;

    const int BT = in_sizes[1];          // B*T
    const int B = BATCH;
    const int T = BT / B;                // 1024
    const int D = in_sizes[0] / BT;      // 768
    const int max_len = out_size / (B * D);

    int* cs = (int*)d_ws;  // B*T ints = 128 KB

    cumsum_kernel<<<B, T, T * sizeof(int), stream>>>(dur, cs, T);

    dim3 block(64, 4);
    dim3 grid((max_len + 3) / 4, B);
    expand_kernel<<<grid, block, 0, stream>>>(x, cs, out, T, D, max_len);
}

// Round 2
// 105.658 us; speedup vs baseline: 1.5120x; 1.5120x over previous
//
#include <hip/hip_runtime.h>

#define BATCH 32

// ---------------------------------------------------------------------------
// Kernel 1: per-row inclusive cumsum of dur [B, T] -> cs [B, T].
// One block of T threads per row; shfl wave-scan + LDS partial scan (3 barriers).
// ---------------------------------------------------------------------------
__global__ void cumsum_kernel(const int* __restrict__ dur, int* __restrict__ cs, int T) {
    const int b = blockIdx.x;
    const int tid = threadIdx.x;          // 0..T-1 (T=1024)
    const int lane = tid & 63;
    const int w = tid >> 6;               // wave id, 0..15

    int v = dur[b * T + tid];

    // inclusive scan within wave (64 lanes)
    #pragma unroll
    for (int off = 1; off < 64; off <<= 1) {
        int u = __shfl_up(v, off, 64);
        if (lane >= off) v += u;
    }

    __shared__ int part[16];
    if (lane == 63) part[w] = v;
    __syncthreads();

    if (w == 0 && lane < 16) {
        int p = part[lane];
        #pragma unroll
        for (int off = 1; off < 16; off <<= 1) {
            int u = __shfl_up(p, off, 16);
            if (lane >= off) p += u;
        }
        part[lane] = p;
    }
    __syncthreads();

    int add = (w > 0) ? part[w - 1] : 0;
    cs[b * T + tid] = v + add;
}

// ---------------------------------------------------------------------------
// Kernel 2: expand by SOURCE frame. One 64-lane wave per (b, t_in).
// Load the frame once (3 x float4 per lane), store it dur times to
// consecutive output rows [cs[t-1], cs[t]). No search, no redundant reads.
// blockDim = (64, 4); grid = (T/4, B).
// ---------------------------------------------------------------------------
__global__ void expand_kernel(const float* __restrict__ x,
                              const int* __restrict__ cs,
                              float* __restrict__ out,
                              int T, int D, int max_len) {
    const int b = blockIdx.y;
    const int tin = blockIdx.x * blockDim.y + threadIdx.y;
    if (tin >= T) return;

    const int* __restrict__ csrow = cs + b * T;
    const int end = csrow[tin];
    const int start = (tin == 0) ? 0 : csrow[tin - 1];
    if (start == end) return;             // dur == 0

    const int lane = threadIdx.x;         // 0..63
    const float4* __restrict__ sp =
        reinterpret_cast<const float4*>(x + ((size_t)b * T + tin) * D);

    // D = 768 floats -> 192 float4 -> 3 per lane
    const float4 v0 = sp[lane];
    const float4 v1 = sp[lane + 64];
    const float4 v2 = sp[lane + 128];

    float4* __restrict__ dst =
        reinterpret_cast<float4*>(out + ((size_t)b * max_len + start) * D);
    const int d4 = D >> 2;                // 192
    for (int j = start; j < end; ++j) {
        dst[lane]       = v0;
        dst[lane + 64]  = v1;
        dst[lane + 128] = v2;
        dst += d4;
    }
}

// ---------------------------------------------------------------------------
// Kernel 3: zero-fill the padded tail rows t in [total_b, max_len).
// One wave per output row; early-exit if t < total.
// ---------------------------------------------------------------------------
__global__ void zerotail_kernel(const int* __restrict__ cs,
                                float* __restrict__ out,
                                int T, int D, int max_len) {
    const int b = blockIdx.y;
    const int t = blockIdx.x * blockDim.y + threadIdx.y;
    if (t >= max_len) return;
    const int total = cs[b * T + T - 1];
    if (t < total) return;

    const int lane = threadIdx.x;
    float4* __restrict__ dst =
        reinterpret_cast<float4*>(out + ((size_t)b * max_len + t) * D);
    const float4 z = make_float4(0.f, 0.f, 0.f, 0.f);
    dst[lane]       = z;
    dst[lane + 64]  = z;
    dst[lane + 128] = z;
}

extern "C" void kernel_launch(void* const* d_in, const int* in_sizes, int n_in,
                              void* d_out, int out_size, void* d_ws, size_t ws_size,
                              hipStream_t stream) {
    const float* x = (const float*)d_in[0];
    const int* dur = (const int*)d_in[1];
    float* out = (float*)d_out;

    const int BT = in_sizes[1];          // B*T
    const int B = BATCH;
    const int T = BT / B;                // 1024
    const int D = in_sizes[0] / BT;      // 768
    const int max_len = out_size / (B * D);

    int* cs = (int*)d_ws;                // B*T ints = 128 KB

    cumsum_kernel<<<B, T, 0, stream>>>(dur, cs, T);

    dim3 block(64, 4);
    dim3 grid_e((T + 3) / 4, B);
    expand_kernel<<<grid_e, block, 0, stream>>>(x, cs, out, T, D, max_len);

    dim3 grid_z((max_len + 3) / 4, B);
    zerotail_kernel<<<grid_z, block, 0, stream>>>(cs, out, T, D, max_len);
}

// Round 4
// 97.831 us; speedup vs baseline: 1.6329x; 1.0800x over previous
//
#include <hip/hip_runtime.h>

#define BATCH 32

// clang native vector type — __builtin_nontemporal_* requires a real vector,
// not HIP's float4 struct.
typedef float f32x4 __attribute__((ext_vector_type(4)));

// ---------------------------------------------------------------------------
// Kernel 1: per-row inclusive cumsum of dur [B, T] -> cs [B, T].
// One block of T threads per row; shfl wave-scan + LDS partial combine.
// ---------------------------------------------------------------------------
__global__ void cumsum_kernel(const int* __restrict__ dur, int* __restrict__ cs, int T) {
    const int b = blockIdx.x;
    const int tid = threadIdx.x;          // 0..T-1 (T=1024)
    const int lane = tid & 63;
    const int w = tid >> 6;               // wave id, 0..15

    int v = dur[b * T + tid];

    #pragma unroll
    for (int off = 1; off < 64; off <<= 1) {
        int u = __shfl_up(v, off, 64);
        if (lane >= off) v += u;
    }

    __shared__ int part[16];
    if (lane == 63) part[w] = v;
    __syncthreads();

    if (w == 0 && lane < 16) {
        int p = part[lane];
        #pragma unroll
        for (int off = 1; off < 16; off <<= 1) {
            int u = __shfl_up(p, off, 16);
            if (lane >= off) p += u;
        }
        part[lane] = p;
    }
    __syncthreads();

    int add = (w > 0) ? part[w - 1] : 0;
    cs[b * T + tid] = v + add;
}

// ---------------------------------------------------------------------------
// Kernel 2 (fused): expand by source frame + zero-fill padded tail.
// Row-id r = blockIdx.x*4 + threadIdx.y over [0, T + max_len):
//   r <  T : wave loads frame r once (3 x 16B/lane) and stores it to
//            output rows [cs[r-1], cs[r]).
//   r >= T : t = r - T; if t >= total, zero-fill output row t.
// Disjoint writes; non-temporal — neither x nor out has reuse.
// ---------------------------------------------------------------------------
__global__ void expand_fused_kernel(const float* __restrict__ x,
                                    const int* __restrict__ cs,
                                    float* __restrict__ out,
                                    int T, int D, int max_len) {
    const int b = blockIdx.y;
    const int r = blockIdx.x * blockDim.y + threadIdx.y;
    const int lane = threadIdx.x;         // 0..63
    const int* __restrict__ csrow = cs + b * T;
    const int d4 = D >> 2;                // 192

    if (r < T) {
        const int end = csrow[r];
        const int start = (r == 0) ? 0 : csrow[r - 1];
        if (start == end) return;         // dur == 0

        const f32x4* __restrict__ sp =
            reinterpret_cast<const f32x4*>(x + ((size_t)b * T + r) * D);
        const f32x4 v0 = __builtin_nontemporal_load(&sp[lane]);
        const f32x4 v1 = __builtin_nontemporal_load(&sp[lane + 64]);
        const f32x4 v2 = __builtin_nontemporal_load(&sp[lane + 128]);

        f32x4* __restrict__ dst =
            reinterpret_cast<f32x4*>(out + ((size_t)b * max_len + start) * D);
        for (int j = start; j < end; ++j) {
            __builtin_nontemporal_store(v0, &dst[lane]);
            __builtin_nontemporal_store(v1, &dst[lane + 64]);
            __builtin_nontemporal_store(v2, &dst[lane + 128]);
            dst += d4;
        }
    } else {
        const int t = r - T;              // output row index
        if (t >= max_len) return;
        const int total = csrow[T - 1];
        if (t < total) return;

        f32x4* __restrict__ dst =
            reinterpret_cast<f32x4*>(out + ((size_t)b * max_len + t) * D);
        const f32x4 z = (f32x4)(0.f);
        __builtin_nontemporal_store(z, &dst[lane]);
        __builtin_nontemporal_store(z, &dst[lane + 64]);
        __builtin_nontemporal_store(z, &dst[lane + 128]);
    }
}

extern "C" void kernel_launch(void* const* d_in, const int* in_sizes, int n_in,
                              void* d_out, int out_size, void* d_ws, size_t ws_size,
                              hipStream_t stream) {
    const float* x = (const float*)d_in[0];
    const int* dur = (const int*)d_in[1];
    float* out = (float*)d_out;

    const int BT = in_sizes[1];          // B*T
    const int B = BATCH;
    const int T = BT / B;                // 1024
    const int D = in_sizes[0] / BT;      // 768
    const int max_len = out_size / (B * D);

    int* cs = (int*)d_ws;                // B*T ints = 128 KB

    cumsum_kernel<<<B, T, 0, stream>>>(dur, cs, T);

    const int rows = T + max_len;
    dim3 block(64, 4);
    dim3 grid((rows + 3) / 4, B);
    expand_fused_kernel<<<grid, block, 0, stream>>>(x, cs, out, T, D, max_len);
}

// Round 5
// 95.557 us; speedup vs baseline: 1.6718x; 1.0238x over previous
//
#include <hip/hip_runtime.h>

#define BATCH 32

typedef float f32x4 __attribute__((ext_vector_type(4)));
typedef int   i32x4 __attribute__((ext_vector_type(4)));

// ---------------------------------------------------------------------------
// Single fused kernel. Block = (64,4) = 4 waves, grid = ((T+max_len)/4, B).
//
// Every block redundantly computes the inclusive cumsum of dur[b][0..T) into
// LDS (dur row = 4 KB, L2-resident; scan cost ~2 us aggregate) — this removes
// the separate cumsum kernel and its stream dependency.
//
// Row r = 4*blockIdx.x + wave:
//   r <  T : expand source frame r -> out rows [cs[r-1], cs[r]).
//            x loaded once per frame (NT loads: zero reuse, keep out of L2).
//            Stores are PLAIN (L2-routed): harness fill kernels prove cached
//            streaming writes hit ~7 TB/s; NT stores measured slower (R4).
//   r >= T : t = r-T; zero-fill out row t if t >= total.
// ---------------------------------------------------------------------------
__global__ void lr_fused_kernel(const float* __restrict__ x,
                                const int* __restrict__ dur,
                                float* __restrict__ out,
                                int T, int D, int max_len) {
    const int b = blockIdx.y;
    const int tid = threadIdx.y * 64 + threadIdx.x;  // 0..255
    const int lane = tid & 63;
    const int w = tid >> 6;                          // wave id 0..3

    __shared__ int cs[1024];   // T = 1024
    __shared__ int part[4];

    // --- block-wide inclusive scan of the dur row (4 ints per thread) ---
    const i32x4* __restrict__ drow = reinterpret_cast<const i32x4*>(dur + b * T);
    const i32x4 d = drow[tid];
    const int s0 = d.x;
    const int s1 = s0 + d.y;
    const int s2 = s1 + d.z;
    const int s3 = s2 + d.w;

    int v = s3;                                      // wave inclusive scan of thread sums
    #pragma unroll
    for (int off = 1; off < 64; off <<= 1) {
        int u = __shfl_up(v, off, 64);
        if (lane >= off) v += u;
    }
    if (lane == 63) part[w] = v;
    __syncthreads();

    int add = 0;
    if (w > 0) add += part[0];
    if (w > 1) add += part[1];
    if (w > 2) add += part[2];

    const int base = add + v - s3;                   // exclusive prefix for this thread
    cs[tid * 4 + 0] = base + s0;
    cs[tid * 4 + 1] = base + s1;
    cs[tid * 4 + 2] = base + s2;
    cs[tid * 4 + 3] = base + s3;
    __syncthreads();

    const int r = blockIdx.x * 4 + w;
    const int d4 = D >> 2;                           // 192

    if (r < T) {
        const int end = cs[r];
        const int start = (r == 0) ? 0 : cs[r - 1];
        if (start == end) return;                    // dur == 0

        const f32x4* __restrict__ sp =
            reinterpret_cast<const f32x4*>(x + ((size_t)b * T + r) * D);
        const f32x4 v0 = __builtin_nontemporal_load(&sp[lane]);
        const f32x4 v1 = __builtin_nontemporal_load(&sp[lane + 64]);
        const f32x4 v2 = __builtin_nontemporal_load(&sp[lane + 128]);

        f32x4* __restrict__ dst =
            reinterpret_cast<f32x4*>(out + ((size_t)b * max_len + start) * D);
        for (int j = start; j < end; ++j) {
            dst[lane]       = v0;
            dst[lane + 64]  = v1;
            dst[lane + 128] = v2;
            dst += d4;
        }
    } else {
        const int t = r - T;                         // output row index
        if (t >= max_len) return;
        const int total = cs[T - 1];
        if (t < total) return;

        f32x4* __restrict__ dst =
            reinterpret_cast<f32x4*>(out + ((size_t)b * max_len + t) * D);
        const f32x4 z = (f32x4)(0.f);
        dst[lane]       = z;
        dst[lane + 64]  = z;
        dst[lane + 128] = z;
    }
}

extern "C" void kernel_launch(void* const* d_in, const int* in_sizes, int n_in,
                              void* d_out, int out_size, void* d_ws, size_t ws_size,
                              hipStream_t stream) {
    const float* x = (const float*)d_in[0];
    const int* dur = (const int*)d_in[1];
    float* out = (float*)d_out;

    const int BT = in_sizes[1];          // B*T
    const int B = BATCH;
    const int T = BT / B;                // 1024
    const int D = in_sizes[0] / BT;      // 768
    const int max_len = out_size / (B * D);

    const int rows = T + max_len;
    dim3 block(64, 4);
    dim3 grid((rows + 3) / 4, B);
    lr_fused_kernel<<<grid, block, 0, stream>>>(x, dur, out, T, D, max_len);
}

// Round 6
// 95.230 us; speedup vs baseline: 1.6775x; 1.0034x over previous
//
#include <hip/hip_runtime.h>

#define BATCH 32

typedef float f32x4 __attribute__((ext_vector_type(4)));
typedef int   i32x4 __attribute__((ext_vector_type(4)));

// ---------------------------------------------------------------------------
// Single fused kernel. Block = (64,4) = 4 waves, grid = (T/4, B).
//
// Each block computes the inclusive cumsum of dur[b][0..T) in LDS (redundant
// per block, but only T/4=256 blocks per batch now). Wave handling frame r:
//   1. expand: load frame r once (3 x 16B NT loads/lane), store to output
//      rows [cs[r-1], cs[r]) with plain (L2-routed) stores.
//   2. tail zero-fill: rows total + r + k*T for k=0,1,... (stride-T loop) —
//      each padded row covered by exactly one wave, no dedicated tail blocks.
// ---------------------------------------------------------------------------
__global__ void lr_fused_kernel(const float* __restrict__ x,
                                const int* __restrict__ dur,
                                float* __restrict__ out,
                                int T, int D, int max_len) {
    const int b = blockIdx.y;
    const int tid = threadIdx.y * 64 + threadIdx.x;  // 0..255
    const int lane = tid & 63;
    const int w = tid >> 6;                          // wave id 0..3

    __shared__ int cs[1024];   // T = 1024
    __shared__ int part[4];

    // --- block-wide inclusive scan of the dur row (4 ints per thread) ---
    const i32x4* __restrict__ drow = reinterpret_cast<const i32x4*>(dur + b * T);
    const i32x4 d = drow[tid];
    const int s0 = d.x;
    const int s1 = s0 + d.y;
    const int s2 = s1 + d.z;
    const int s3 = s2 + d.w;

    int v = s3;                                      // wave-inclusive scan of thread sums
    #pragma unroll
    for (int off = 1; off < 64; off <<= 1) {
        int u = __shfl_up(v, off, 64);
        if (lane >= off) v += u;
    }
    if (lane == 63) part[w] = v;
    __syncthreads();

    int add = 0;
    if (w > 0) add += part[0];
    if (w > 1) add += part[1];
    if (w > 2) add += part[2];

    const int base = add + v - s3;                   // exclusive prefix for this thread
    cs[tid * 4 + 0] = base + s0;
    cs[tid * 4 + 1] = base + s1;
    cs[tid * 4 + 2] = base + s2;
    cs[tid * 4 + 3] = base + s3;
    __syncthreads();

    const int r = blockIdx.x * 4 + w;                // source frame, 0..T-1
    const int d4 = D >> 2;                           // 192
    const int total = cs[T - 1];

    // --- 1. expand source frame r ---
    if (r < T) {
        const int end = cs[r];
        const int start = (r == 0) ? 0 : cs[r - 1];
        if (start != end) {                          // dur > 0
            const f32x4* __restrict__ sp =
                reinterpret_cast<const f32x4*>(x + ((size_t)b * T + r) * D);
            const f32x4 v0 = __builtin_nontemporal_load(&sp[lane]);
            const f32x4 v1 = __builtin_nontemporal_load(&sp[lane + 64]);
            const f32x4 v2 = __builtin_nontemporal_load(&sp[lane + 128]);

            f32x4* __restrict__ dst =
                reinterpret_cast<f32x4*>(out + ((size_t)b * max_len + start) * D);
            for (int j = start; j < end; ++j) {
                dst[lane]       = v0;
                dst[lane + 64]  = v1;
                dst[lane + 128] = v2;
                dst += d4;
            }
        }

        // --- 2. zero-fill padded tail rows total+r, total+r+T, ... ---
        const f32x4 z = (f32x4)(0.f);
        for (int t = total + r; t < max_len; t += T) {
            f32x4* __restrict__ zp =
                reinterpret_cast<f32x4*>(out + ((size_t)b * max_len + t) * D);
            zp[lane]       = z;
            zp[lane + 64]  = z;
            zp[lane + 128] = z;
        }
    }
}

extern "C" void kernel_launch(void* const* d_in, const int* in_sizes, int n_in,
                              void* d_out, int out_size, void* d_ws, size_t ws_size,
                              hipStream_t stream) {
    const float* x = (const float*)d_in[0];
    const int* dur = (const int*)d_in[1];
    float* out = (float*)d_out;

    const int BT = in_sizes[1];          // B*T
    const int B = BATCH;
    const int T = BT / B;                // 1024
    const int D = in_sizes[0] / BT;      // 768
    const int max_len = out_size / (B * D);

    dim3 block(64, 4);
    dim3 grid((T + 3) / 4, B);
    lr_fused_kernel<<<grid, block, 0, stream>>>(x, dur, out, T, D, max_len);
}